// Round 5
// baseline (83.879 us; speedup 1.0000x reference)
//
#include <hip/hip_runtime.h>

#define SS 14
#define NBOX 2
#define CCH 30                           // 5*NBOX + 20 classes
#define TILE_CELLS 64                    // cells per wave-tile
#define TILE_FLOATS (TILE_CELLS * CCH)   // 1920 floats = 7680 bytes
#define WAVES_PER_BLOCK 4
#define NLOAD 15                         // 15 x (64 lanes x 8B) = 7680 B

// Per-cell YOLOv1 loss (identical math to the absmax-0.0 Round-1 kernel).
__device__ __forceinline__ float cell_loss(const float* p, const float* t) {
    float iou0 = 0.f, iou1 = 0.f, loc0 = 0.f, loc1 = 0.f;
#pragma unroll
    for (int b = 0; b < NBOX; ++b) {
        const int o = 5 * b;
        float thw = 0.5f * t[o + 2] * t[o + 2];
        float thh = 0.5f * t[o + 3] * t[o + 3];
        float phw = 0.5f * p[o + 2] * p[o + 2];
        float phh = 0.5f * p[o + 3] * p[o + 3];
        float t0x = t[o + 0] - thw, t0y = t[o + 1] - thh;
        float t1x = t[o + 0] + thw, t1y = t[o + 1] + thh;
        float p0x = p[o + 0] - phw, p0y = p[o + 1] - phh;
        float p1x = p[o + 0] + phw, p1y = p[o + 1] + phh;

        float ltx = fmaxf(t0x, p0x), lty = fmaxf(t0y, p0y);
        float rbx = fminf(t1x, p1x), rby = fminf(t1y, p1y);
        float w = fmaxf(rbx - ltx, 0.0f);
        float h = fmaxf(rby - lty, 0.0f);
        float inter = w * h;
        float a1 = (t1x - t0x) * (t1y - t0y);
        float a2 = (p1x - p0x) * (p1y - p0y);
        float denom = a1 + a2 - inter;
        float iou_b = (denom > 0.0f) ? (inter / denom) : 0.0f;

        float l = 0.0f;
#pragma unroll
        for (int k = 0; k < 4; ++k) {
            float d = p[o + k] - t[o + k];
            l += d * d;
        }
        if (b == 0) { iou0 = iou_b; loc0 = l; }
        else        { iou1 = iou_b; loc1 = l; }
    }

    int sel1 = (iou1 > iou0);               // argmax: first max on ties
    float max_iou = fmaxf(iou0, iou1);
    float loc   = sel1 ? loc1 : loc0;
    float pconf = sel1 ? p[9] : p[4];
    float tconf = sel1 ? t[9] : t[4];

    float cls = 0.0f;
#pragma unroll
    for (int k = 5 * NBOX; k < CCH; ++k) {
        float d = p[k] - t[k];
        cls += d * d;
    }

    float dcon = pconf - max_iou;
    float d4 = p[4] - t[4];
    float d9 = p[9] - t[9];
    float noobj = d4 * d4 + d9 * d9;
    float diou = max_iou - tconf;

    float objf = (t[4] > 0.0f) ? 1.0f : 0.0f;
    return objf * (5.0f * loc + cls + dcon * dcon + diou * diou)
         + (1.0f - objf) * 0.5f * noobj;
}

#define WAIT_VM30 do { asm volatile("s_waitcnt vmcnt(30)" ::: "memory"); \
                       __builtin_amdgcn_sched_barrier(0); } while (0)
#define WAIT_VM0  do { asm volatile("s_waitcnt vmcnt(0)" ::: "memory"); \
                       __builtin_amdgcn_sched_barrier(0); } while (0)
#define WAIT_LGKM0 do { asm volatile("s_waitcnt lgkmcnt(0)" ::: "memory"); \
                        __builtin_amdgcn_sched_barrier(0); } while (0)

__global__ __launch_bounds__(256, 2) void yolov1_loss_kernel(
    const float* __restrict__ pred, const float* __restrict__ target,
    float* __restrict__ out, int ncells, float inv_batch)
{
    // One LDS buffer pair per wave (regs are the second pipeline stage).
    // 4 waves x 15360 B = 61440 B -> 2 blocks/CU = 8 waves/CU.
    __shared__ __align__(16) float lds[WAVES_PER_BLOCK * 2 * TILE_FLOATS];

    const int lane = threadIdx.x & 63;
    const int wid  = threadIdx.x >> 6;
    const int w    = blockIdx.x * WAVES_PER_BLOCK + wid;
    const int W    = gridDim.x * WAVES_PER_BLOCK;
    const int ntiles = ncells / TILE_CELLS;

    float* myp = lds + wid * (2 * TILE_FLOATS);
    float* myt = myp + TILE_FLOATS;

    // coalesced reg staging: instr j loads floats [j*128 + lane*2, +2)
#define ISSUE(RP, RT, TI) do {                                              \
    const float2* gp = (const float2*)pred  + (size_t)(TI) * (TILE_FLOATS/2);\
    const float2* gt = (const float2*)target + (size_t)(TI) * (TILE_FLOATS/2);\
    _Pragma("unroll")                                                        \
    for (int j = 0; j < NLOAD; ++j) {                                        \
        RP[j] = gp[j * 64 + lane];                                           \
        RT[j] = gt[j * 64 + lane];                                           \
    } } while (0)

#define WRITE_LDS(RP, RT) do {                                               \
    _Pragma("unroll")                                                        \
    for (int j = 0; j < NLOAD; ++j) {                                        \
        *(float2*)(myp + j * 128 + lane * 2) = RP[j];                        \
        *(float2*)(myt + j * 128 + lane * 2) = RT[j];                        \
    } } while (0)

#define PROCESS() do {                                                       \
    float p[CCH], t[CCH];                                                    \
    const float2* pl = (const float2*)(myp + lane * CCH);                    \
    const float2* tl = (const float2*)(myt + lane * CCH);                    \
    _Pragma("unroll")                                                        \
    for (int k = 0; k < CCH / 2; ++k) {                                      \
        float2 a = pl[k]; p[2 * k] = a.x; p[2 * k + 1] = a.y;                \
        float2 b = tl[k]; t[2 * k] = b.x; t[2 * k + 1] = b.y;                \
    }                                                                        \
    acc += cell_loss(p, t); } while (0)

    float2 rAp[NLOAD], rAt[NLOAD], rBp[NLOAD], rBt[NLOAD];

    float acc = 0.0f;
    int cur = w;
    if (cur < ntiles) {
        ISSUE(rAp, rAt, cur);
        for (;;) {
            // ---- half 1: compute A, prefetch into B ----
            int nxt = cur + W;
            bool more = nxt < ntiles;
            if (more) { ISSUE(rBp, rBt, nxt); WAIT_VM30; }
            else      { WAIT_VM0; }
            WRITE_LDS(rAp, rAt);
            WAIT_LGKM0;             // writes visible for reads; rA regs free
            PROCESS();              // ds_reads ordered before next ds_write
            if (!more) break;
            cur = nxt;

            // ---- half 2: compute B, prefetch into A ----
            nxt = cur + W;
            more = nxt < ntiles;
            if (more) { ISSUE(rAp, rAt, nxt); WAIT_VM30; }
            else      { WAIT_VM0; }
            WRITE_LDS(rBp, rBt);
            WAIT_LGKM0;
            PROCESS();
            if (!more) break;
            cur = nxt;
        }
    }

    // remainder cells (ncells % 64 != 0) — zero iterations for this shape
    for (int cell = ntiles * TILE_CELLS + w * 64 + lane; cell < ncells;
         cell += W * 64) {
        float p[CCH], t[CCH];
        const float2* pp = (const float2*)(pred + (size_t)cell * CCH);
        const float2* tp = (const float2*)(target + (size_t)cell * CCH);
#pragma unroll
        for (int k = 0; k < CCH / 2; ++k) {
            float2 a = pp[k]; p[2 * k] = a.x; p[2 * k + 1] = a.y;
            float2 b = tp[k]; t[2 * k] = b.x; t[2 * k + 1] = b.y;
        }
        acc += cell_loss(p, t);
    }

    // wave(64) shuffle reduction, one atomic per wave
#pragma unroll
    for (int off = 32; off > 0; off >>= 1)
        acc += __shfl_down(acc, off, 64);
    if (lane == 0)
        atomicAdd(out, acc * inv_batch);
}

extern "C" void kernel_launch(void* const* d_in, const int* in_sizes, int n_in,
                              void* d_out, int out_size, void* d_ws, size_t ws_size,
                              hipStream_t stream) {
    const float* pred = (const float*)d_in[0];
    const float* target = (const float*)d_in[1];
    float* out = (float*)d_out;

    int ncells = in_sizes[0] / CCH;           // batch * S * S = 1,605,632
    int batch = ncells / (SS * SS);           // 8192
    float inv_batch = 1.0f / (float)batch;

    hipMemsetAsync(d_out, 0, sizeof(float) * out_size, stream);

    const int threads = 256;                   // 4 waves/block
    int blocks = 512;                          // 2 blocks/CU -> 8 waves/CU
    yolov1_loss_kernel<<<blocks, threads, 0, stream>>>(pred, target, out,
                                                       ncells, inv_batch);
}